// Round 5
// baseline (1542.609 us; speedup 1.0000x reference)
//
#include <hip/hip_runtime.h>

#define Bdim 512
#define Tt   256
#define Ii   128
#define Hh   512
#define BM   16     // batch rows per group
#define NGRP 32
#define NSL  8      // column slices (WGs) per group

typedef __attribute__((ext_vector_type(4))) float f32x4;
typedef __attribute__((ext_vector_type(8))) short short8;
typedef __attribute__((ext_vector_type(2))) unsigned long long u64x2;

__device__ __forceinline__ unsigned short f2bf(float f) {
    unsigned u = __builtin_bit_cast(unsigned, f);
    u += 0x7fffu + ((u >> 16) & 1u);   // round-to-nearest-even
    return (unsigned short)(u >> 16);
}

__device__ __forceinline__ short8 pack_bf8(f32x4 lo, f32x4 hi) {
    short8 r;
    r[0] = (short)f2bf(lo[0]); r[1] = (short)f2bf(lo[1]);
    r[2] = (short)f2bf(lo[2]); r[3] = (short)f2bf(lo[3]);
    r[4] = (short)f2bf(hi[0]); r[5] = (short)f2bf(hi[1]);
    r[6] = (short)f2bf(hi[2]); r[7] = (short)f2bf(hi[3]);
    return r;
}

// weight fragment: B[k][n] = W[row][k], lane holds k = kbase..kbase+7 for its column
__device__ __forceinline__ short8 load_wfrag(const float* __restrict__ Whh,
                                             const float* __restrict__ Wih,
                                             int row, int k) {
    const float* p = (k < Hh) ? (Whh + row * Hh + k) : (Wih + row * Ii + (k - Hh));
    f32x4 lo = *(const f32x4*)p;
    f32x4 hi = *(const f32x4*)(p + 4);
    return pack_bf8(lo, hi);
}

// x-tile LDS address: [16 rows][128 bf16], XOR-swizzled (stride 256B -> 16-way
// conflict without it)
__device__ __forceinline__ int ldsx(int row, int kbyte) {
    return (row * 256 + kbyte) ^ ((row & 7) << 4);
}

__device__ __forceinline__ float sigm(float v)  { return 1.f / (1.f + __expf(-v)); }
__device__ __forceinline__ float tanhf_(float v){ return 1.f - 2.f / (__expf(2.f * v) + 1.f); }

__global__ void init_flags(int* f, int n) {
    int i = blockIdx.x * blockDim.x + threadIdx.x;
    if (i < n) f[i] = -1;
}

__global__ __launch_bounds__(256, 1)
void gru_persist(const float* __restrict__ x,   const float* __restrict__ Wih,
                 const float* __restrict__ Whh, const float* __restrict__ bih,
                 const float* __restrict__ bhh, const float* __restrict__ Wlin,
                 const float* __restrict__ blin, float* __restrict__ out,
                 unsigned short* __restrict__ hbuf, int* __restrict__ flags)
{
    __shared__ __align__(16) unsigned char lX[16 * 256];   // [16 rows][128 bf16]

    const int wg   = blockIdx.x;
    const int tid  = threadIdx.x;
    const int lane = tid & 63;
    const int w    = tid >> 6;          // wave 0..3
    // Keep a group's 8 slices on nearby CUs (perf heuristic only; correctness
    // does not depend on placement — all sync is agent-scope at the LLC).
    const int xcd8 = wg & 7, lg = (wg >> 3) & 3, sl = wg >> 5;
    const int g   = xcd8 * 4 + lg;      // group 0..31
    const int b0  = g * BM;
    const int jw  = sl * 64 + w * 16;   // this wave's 16 h-columns
    const int col16 = lane & 15;
    const int kg8   = (lane >> 4) * 8;  // k sub-offset within a K=32 tile
    const int colg  = jw + col16;       // global h-column this lane owns

    // biases (per-lane, per its column)
    const float br  = bih[colg] + bhh[colg];
    const float bz  = bih[Hh + colg] + bhh[Hh + colg];
    const float bxn = bih[2 * Hh + colg];
    const float bhn = bhh[2 * Hh + colg];

    // ---- load weight B-fragments once into registers/AGPRs (persistent) ----
    short8 wR[20], wZ[20], wN[20];
#pragma unroll
    for (int kt = 0; kt < 20; ++kt) {
        int k = kt * 32 + kg8;
        wR[kt] = load_wfrag(Whh, Wih, colg, k);
        wZ[kt] = load_wfrag(Whh, Wih, Hh + colg, k);
        wN[kt] = load_wfrag(Whh, Wih, 2 * Hh + colg, k);
    }

    unsigned short* ub0 = hbuf;
    unsigned short* ub1 = hbuf + Bdim * Hh;
    int* gflags = flags + g * NSL;
    const unsigned long long* fp64 = (const unsigned long long*)gflags;

    f32x4 hreg = {0.f, 0.f, 0.f, 0.f};  // own h tile, exact fp32 carry

    // x prefetch for t=0 (plain compiler-tracked loads)
    const int xrow0 = tid >> 4,         xc40 = tid & 15;        // 16 chunks/row of 8B
    f32x4 xr0 = *(const f32x4*)(x + ((size_t)(b0 + xrow0) * Tt + 0) * Ii + xc40 * 8);
    f32x4 xr1 = *(const f32x4*)(x + ((size_t)(b0 + xrow0) * Tt + 0) * Ii + xc40 * 8 + 4);

#pragma unroll 1
    for (int t = 0; t < Tt; ++t) {
        const int pin = t & 1;
        unsigned short*       hout = pin ? ub0 : ub1;
        const unsigned short* hin  = pin ? ub1 : ub0;

        // ---- stage x_t (prefetched regs) -> bf16 LDS ----
        {
            unsigned long long pk0 = (unsigned long long)f2bf(xr0[0])
                                   | ((unsigned long long)f2bf(xr0[1]) << 16)
                                   | ((unsigned long long)f2bf(xr0[2]) << 32)
                                   | ((unsigned long long)f2bf(xr0[3]) << 48);
            *(unsigned long long*)(lX + ldsx(xrow0, xc40 * 16)) = pk0;
            unsigned long long pk1 = (unsigned long long)f2bf(xr1[0])
                                   | ((unsigned long long)f2bf(xr1[1]) << 16)
                                   | ((unsigned long long)f2bf(xr1[2]) << 32)
                                   | ((unsigned long long)f2bf(xr1[3]) << 48);
            *(unsigned long long*)(lX + ldsx(xrow0, xc40 * 16 + 8)) = pk1;
        }
        __syncthreads();

        // prefetch x_{t+1} (overlaps poll + panel load + MFMAs)
        if (t + 1 < Tt) {
            xr0 = *(const f32x4*)(x + ((size_t)(b0 + xrow0) * Tt + (t + 1)) * Ii + xc40 * 8);
            xr1 = *(const f32x4*)(x + ((size_t)(b0 + xrow0) * Tt + (t + 1)) * Ii + xc40 * 8 + 4);
        }

        f32x4 accR = {0,0,0,0}, accZ = {0,0,0,0}, accNH = {0,0,0,0}, accNX = {0,0,0,0};

        // ---- x-part MFMAs (independent of h -> overlap with the flag wait) ----
#pragma unroll
        for (int kt = 0; kt < 4; ++kt) {
            short8 a = *(const short8*)(lX + ldsx(col16, (kt * 32 + kg8) * 2));
            accR  = __builtin_amdgcn_mfma_f32_16x16x32_bf16(a, wR[16 + kt], accR, 0, 0, 0);
            accZ  = __builtin_amdgcn_mfma_f32_16x16x32_bf16(a, wZ[16 + kt], accZ, 0, 0, 0);
            accNX = __builtin_amdgcn_mfma_f32_16x16x32_bf16(a, wN[16 + kt], accNX, 0, 0, 0);
        }

        if (t > 0) {
            // ---- wait for the OTHER 7 slices to have published h_{t-1}.
            //      Per-wave poll, relaxed 8B loads over the 8 slice-flags;
            //      own slice skipped (own stores already drained). Bounded
            //      so a protocol bug is a wrong answer, not a timeout. ----
            {
                int spin = 0;
                bool ok = false;
                while (!ok && spin < (1 << 20)) {
                    int mn = 0x7fffffff;
#pragma unroll
                    for (int j = 0; j < 4; ++j) {
                        unsigned long long v = __hip_atomic_load(
                            fp64 + j, __ATOMIC_RELAXED, __HIP_MEMORY_SCOPE_AGENT);
                        int a = (int)(unsigned)(v & 0xffffffffu);
                        int b = (int)(unsigned)(v >> 32);
                        if (2 * j     != sl && a < mn) mn = a;
                        if (2 * j + 1 != sl && b < mn) mn = b;
                    }
                    ok = (mn >= t - 1);
                    ++spin;
                }
            }
            __builtin_amdgcn_sched_barrier(0);

            // ---- load h A-fragments DIRECTLY from the bf16 exchange buffer:
            //      lane's fragment = 16 contiguous bytes at
            //      h[b0 + (lane&15)][kt*32 + (lane>>4)*8]  (proven 8B atomics) ----
            unsigned long long hv[32];
            const unsigned short* hrow = hin + (size_t)(b0 + col16) * Hh + kg8;
#pragma unroll
            for (int kt = 0; kt < 16; ++kt) {
                hv[2 * kt]     = __hip_atomic_load(
                    (const unsigned long long*)(hrow + kt * 32),
                    __ATOMIC_RELAXED, __HIP_MEMORY_SCOPE_AGENT);
                hv[2 * kt + 1] = __hip_atomic_load(
                    (const unsigned long long*)(hrow + kt * 32 + 4),
                    __ATOMIC_RELAXED, __HIP_MEMORY_SCOPE_AGENT);
            }
            // ---- h-part MFMAs (compiler interleaves waits with issues) ----
#pragma unroll
            for (int kt = 0; kt < 16; ++kt) {
                u64x2 p; p[0] = hv[2 * kt]; p[1] = hv[2 * kt + 1];
                short8 a = __builtin_bit_cast(short8, p);
                accR  = __builtin_amdgcn_mfma_f32_16x16x32_bf16(a, wR[kt], accR, 0, 0, 0);
                accZ  = __builtin_amdgcn_mfma_f32_16x16x32_bf16(a, wZ[kt], accZ, 0, 0, 0);
                accNH = __builtin_amdgcn_mfma_f32_16x16x32_bf16(a, wN[kt], accNH, 0, 0, 0);
            }
        }

        // ---- gates + state update (C/D layout: col=lane&15, row=(lane>>4)*4+i) ----
        // publish h_t as bf16: pair adjacent lanes (adjacent cols) via shfl,
        // even lane does one proven 4B relaxed-agent atomic store per row.
#pragma unroll
        for (int i = 0; i < 4; ++i) {
            int row = (lane >> 4) * 4 + i;
            float hp = hreg[i];
            float r  = sigm(accR[i] + br);
            float z  = sigm(accZ[i] + bz);
            float n  = tanhf_(accNX[i] + bxn + r * (accNH[i] + bhn));
            float hv = (1.f - z) * n + z * hp;
            hreg[i] = hv;
            unsigned mybf = f2bf(hv);
            unsigned other = (unsigned)__shfl_xor((int)mybf, 1);
            if ((lane & 1) == 0) {
                unsigned pk = mybf | (other << 16);
                __hip_atomic_store(
                    (unsigned*)(hout + (size_t)(b0 + row) * Hh + colg), pk,
                    __ATOMIC_RELAXED, __HIP_MEMORY_SCOPE_AGENT);
            }
        }
        // drain own stores to the coherence point, then WG-wide agreement,
        // then publish this slice's step number (plain store, no RMW).
        asm volatile("s_waitcnt vmcnt(0)" ::: "memory");
        __syncthreads();
        if (tid == 0)
            __hip_atomic_store(gflags + sl, t, __ATOMIC_RELAXED,
                               __HIP_MEMORY_SCOPE_AGENT);
    }

    // ---- final linear: slice-0 WG of each group computes out[b0..b0+15] ----
    if (sl == 0) {
        {
            int spin = 0;
            bool ok = false;
            while (!ok && spin < (1 << 20)) {
                int mn = 0x7fffffff;
#pragma unroll
                for (int j = 0; j < 4; ++j) {
                    unsigned long long v = __hip_atomic_load(
                        fp64 + j, __ATOMIC_RELAXED, __HIP_MEMORY_SCOPE_AGENT);
                    int a = (int)(unsigned)(v & 0xffffffffu);
                    int b = (int)(unsigned)(v >> 32);
                    if (2 * j     != sl && a < mn) mn = a;
                    if (2 * j + 1 != sl && b < mn) mn = b;
                }
                ok = (mn >= Tt - 1);
                ++spin;
            }
        }
        __builtin_amdgcn_sched_barrier(0);
        __syncthreads();
        const unsigned short* hf = ub0;   // t=255: pin=1 -> wrote ub0
        const float bl = blin[0];
        for (int rr = w; rr < BM; rr += 4) {
            int b = b0 + rr;
            unsigned long long v0 = __hip_atomic_load(
                (const unsigned long long*)(hf + (size_t)b * Hh + lane * 8),
                __ATOMIC_RELAXED, __HIP_MEMORY_SCOPE_AGENT);
            unsigned long long v1 = __hip_atomic_load(
                (const unsigned long long*)(hf + (size_t)b * Hh + lane * 8 + 4),
                __ATOMIC_RELAXED, __HIP_MEMORY_SCOPE_AGENT);
            float sum = 0.f;
#pragma unroll
            for (int k = 0; k < 4; ++k) {
                unsigned u0 = (unsigned)((v0 >> (16 * k)) & 0xffffu);
                unsigned u1 = (unsigned)((v1 >> (16 * k)) & 0xffffu);
                float f0 = __builtin_bit_cast(float, u0 << 16);
                float f1 = __builtin_bit_cast(float, u1 << 16);
                sum += f0 * Wlin[lane * 8 + k] + f1 * Wlin[lane * 8 + 4 + k];
            }
#pragma unroll
            for (int off = 32; off; off >>= 1) sum += __shfl_xor(sum, off);
            if (lane == 0) out[b] = sum + bl;
        }
    }
}

extern "C" void kernel_launch(void* const* d_in, const int* in_sizes, int n_in,
                              void* d_out, int out_size, void* d_ws, size_t ws_size,
                              hipStream_t stream) {
    const float* x    = (const float*)d_in[0];
    const float* Wih  = (const float*)d_in[1];
    const float* Whh  = (const float*)d_in[2];
    const float* bih  = (const float*)d_in[3];
    const float* bhh  = (const float*)d_in[4];
    const float* Wlin = (const float*)d_in[5];
    const float* blin = (const float*)d_in[6];
    float* out  = (float*)d_out;

    unsigned short* hbuf = (unsigned short*)d_ws;   // 2 x 512x512 bf16 = 1 MB
    int* flags = (int*)((char*)d_ws + 2ull * Bdim * Hh * sizeof(unsigned short));

    init_flags<<<1, 256, 0, stream>>>(flags, NGRP * NSL);
    gru_persist<<<256, 256, 0, stream>>>(x, Wih, Whh, bih, bhh, Wlin, blin, out,
                                         hbuf, flags);
}

// Round 6
// 1319.473 us; speedup vs baseline: 1.1691x; 1.1691x over previous
//
#include <hip/hip_runtime.h>

#define Bdim 512
#define Tt   256
#define Ii   128
#define Hh   512
#define BM   16     // batch rows per group
#define NGRP 32
#define NSL  8      // column slices (WGs) per group

typedef __attribute__((ext_vector_type(4))) float f32x4;
typedef __attribute__((ext_vector_type(8))) short short8;
typedef __attribute__((ext_vector_type(2))) unsigned long long u64x2;

__device__ __forceinline__ unsigned short f2bf(float f) {
    unsigned u = __builtin_bit_cast(unsigned, f);
    u += 0x7fffu + ((u >> 16) & 1u);   // round-to-nearest-even
    return (unsigned short)(u >> 16);
}

__device__ __forceinline__ short8 pack_bf8(f32x4 lo, f32x4 hi) {
    short8 r;
    r[0] = (short)f2bf(lo[0]); r[1] = (short)f2bf(lo[1]);
    r[2] = (short)f2bf(lo[2]); r[3] = (short)f2bf(lo[3]);
    r[4] = (short)f2bf(hi[0]); r[5] = (short)f2bf(hi[1]);
    r[6] = (short)f2bf(hi[2]); r[7] = (short)f2bf(hi[3]);
    return r;
}

// weight A-fragment: lane holds W[row = rowbase + (lane&15)][k..k+8)
__device__ __forceinline__ short8 load_wfrag(const float* __restrict__ Whh,
                                             const float* __restrict__ Wih,
                                             int row, int k) {
    const float* p = (k < Hh) ? (Whh + row * Hh + k) : (Wih + row * Ii + (k - Hh));
    f32x4 lo = *(const f32x4*)p;
    f32x4 hi = *(const f32x4*)(p + 4);
    return pack_bf8(lo, hi);
}

__device__ __forceinline__ float sigm(float v)  { return 1.f / (1.f + __expf(-v)); }
__device__ __forceinline__ float tanhf_(float v){ return 1.f - 2.f / (__expf(2.f * v) + 1.f); }

__global__ void init_flags(int* f, int n) {
    int i = blockIdx.x * blockDim.x + threadIdx.x;
    if (i < n) f[i] = -1;
}

// Exchange buffer F: fragment-ordered bf16 h state.
// F entry (buf, g, kt, l) = h[batch = l&15][k = kt*32 + (l>>4)*8 .. +8) as 8 bf16
// (16B). u64 index = (buf*NGRP+g)*2048 + kt*128 + l*2.
__global__ __launch_bounds__(256, 1)
void gru_persist(const float* __restrict__ x,   const float* __restrict__ Wih,
                 const float* __restrict__ Whh, const float* __restrict__ bih,
                 const float* __restrict__ bhh, const float* __restrict__ Wlin,
                 const float* __restrict__ blin, float* __restrict__ out,
                 unsigned long long* __restrict__ F, int* __restrict__ flags)
{
    const int wg   = blockIdx.x;
    const int tid  = threadIdx.x;
    const int lane = tid & 63;
    const int w    = tid >> 6;          // wave 0..3
    // Keep a group's 8 slices on nearby CUs (perf heuristic only; correctness
    // does not depend on placement — all sync is agent-scope at the LLC).
    const int xcd8 = wg & 7, lg = (wg >> 3) & 3, sl = wg >> 5;
    const int gi  = xcd8 * 4 + lg;      // group 0..31
    const int b0  = gi * BM;
    const int jw  = sl * 64 + w * 16;   // this wave's 16 gate/h columns
    const int l15 = lane & 15;
    const int cg  = lane >> 4;          // 4-col chunk / k-half selector
    const int kg8 = cg * 8;
    const int colg = jw + l15;          // gate row this lane holds weights for
    const int kt_w = sl * 2 + (w >> 1); // the k-tile this wave's columns fall in

    // biases: lane's 4 gate columns are jw + cg*4 + i (D layout: col=batch=lane&15,
    // row=gate=(lane>>4)*4+i, m89-verified with roles swapped)
    f32x4 brv, bzv, bxnv, bhnv;
#pragma unroll
    for (int i = 0; i < 4; ++i) {
        int c = jw + cg * 4 + i;
        brv[i]  = bih[c] + bhh[c];
        bzv[i]  = bih[Hh + c] + bhh[Hh + c];
        bxnv[i] = bih[2 * Hh + c];
        bhnv[i] = bhh[2 * Hh + c];
    }

    // ---- weight A-fragments, resident for the whole kernel ----
    short8 wR[20], wZ[20], wN[20];
#pragma unroll
    for (int kt = 0; kt < 20; ++kt) {
        int k = kt * 32 + kg8;
        wR[kt] = load_wfrag(Whh, Wih, colg, k);
        wZ[kt] = load_wfrag(Whh, Wih, Hh + colg, k);
        wN[kt] = load_wfrag(Whh, Wih, 2 * Hh + colg, k);
    }

    int* gflags = flags + gi * 32;
    const int* myflag = gflags + (lane & 31);   // each lane polls one wave-flag

    f32x4 hreg = {0.f, 0.f, 0.f, 0.f};  // own (batch=l15, cols jw+cg*4..+4), fp32 carry

    // x B-fragment prefetch for t=0: lane needs x[b0+l15][t][kt*32+kg8 .. +8)
    f32x4 xa[4], xb[4];
    {
        const float* xp = x + ((size_t)(b0 + l15) * Tt + 0) * Ii + kg8;
#pragma unroll
        for (int kt = 0; kt < 4; ++kt) {
            xa[kt] = *(const f32x4*)(xp + kt * 32);
            xb[kt] = *(const f32x4*)(xp + kt * 32 + 4);
        }
    }

#pragma unroll 1
    for (int t = 0; t < Tt; ++t) {
        const int wb = t & 1, rb = wb ^ 1;

        f32x4 accR = {0,0,0,0}, accZ = {0,0,0,0}, accNH = {0,0,0,0}, accNX = {0,0,0,0};

        // ---- x-part MFMAs from prefetched registers (A=W, B=x^T) ----
#pragma unroll
        for (int kt = 0; kt < 4; ++kt) {
            short8 bx = pack_bf8(xa[kt], xb[kt]);
            accR  = __builtin_amdgcn_mfma_f32_16x16x32_bf16(wR[16 + kt], bx, accR, 0, 0, 0);
            accZ  = __builtin_amdgcn_mfma_f32_16x16x32_bf16(wZ[16 + kt], bx, accZ, 0, 0, 0);
            accNX = __builtin_amdgcn_mfma_f32_16x16x32_bf16(wN[16 + kt], bx, accNX, 0, 0, 0);
        }

        // prefetch x_{t+1} (overlaps poll + fragment loads + MFMAs)
        if (t + 1 < Tt) {
            const float* xp = x + ((size_t)(b0 + l15) * Tt + (t + 1)) * Ii + kg8;
#pragma unroll
            for (int kt = 0; kt < 4; ++kt) {
                xa[kt] = *(const f32x4*)(xp + kt * 32);
                xb[kt] = *(const f32x4*)(xp + kt * 32 + 4);
            }
        }

        if (t > 0) {
            // ---- wait for all 32 producer waves to publish h_{t-1}:
            //      one 4B flag load per lane, wave-wide __all. Bounded. ----
            int spin = 0;
            for (;;) {
                int f = __hip_atomic_load(myflag, __ATOMIC_RELAXED,
                                          __HIP_MEMORY_SCOPE_AGENT);
                if (__all(f >= t - 1) || ++spin >= (1 << 20)) break;
            }
            __builtin_amdgcn_sched_barrier(0);

            // ---- coalesced fragment loads: 16B per lane per kt ----
            unsigned long long hv[32];
            const unsigned long long* Fr = F + (size_t)(rb * NGRP + gi) * 2048 + lane * 2;
#pragma unroll
            for (int kt = 0; kt < 16; ++kt) {
                hv[2 * kt]     = __hip_atomic_load(Fr + kt * 128,
                                     __ATOMIC_RELAXED, __HIP_MEMORY_SCOPE_AGENT);
                hv[2 * kt + 1] = __hip_atomic_load(Fr + kt * 128 + 1,
                                     __ATOMIC_RELAXED, __HIP_MEMORY_SCOPE_AGENT);
            }
            // ---- h-part MFMAs ----
#pragma unroll
            for (int kt = 0; kt < 16; ++kt) {
                u64x2 p; p[0] = hv[2 * kt]; p[1] = hv[2 * kt + 1];
                short8 bh = __builtin_bit_cast(short8, p);
                accR  = __builtin_amdgcn_mfma_f32_16x16x32_bf16(wR[kt], bh, accR, 0, 0, 0);
                accZ  = __builtin_amdgcn_mfma_f32_16x16x32_bf16(wZ[kt], bh, accZ, 0, 0, 0);
                accNH = __builtin_amdgcn_mfma_f32_16x16x32_bf16(wN[kt], bh, accNH, 0, 0, 0);
            }
        }

        // ---- gates + state update (lane: batch=l15, cols jw+cg*4 .. +4) ----
        f32x4 hnew;
#pragma unroll
        for (int i = 0; i < 4; ++i) {
            float r = sigm(accR[i] + brv[i]);
            float z = sigm(accZ[i] + bzv[i]);
            float n = tanhf_(accNX[i] + bxnv[i] + r * (accNH[i] + bhnv[i]));
            hnew[i] = (1.f - z) * n + z * hreg[i];
        }
        hreg = hnew;

        // ---- publish: pack 4 bf16, pair with neighbor chunk via shfl_xor(16),
        //      even-chunk lanes store the ordered 16B fragment (2x8B atomics) ----
        unsigned long long mine =
              (unsigned long long)f2bf(hnew[0])
            | ((unsigned long long)f2bf(hnew[1]) << 16)
            | ((unsigned long long)f2bf(hnew[2]) << 32)
            | ((unsigned long long)f2bf(hnew[3]) << 48);
        unsigned long long part = __shfl_xor(mine, 16);
        if ((cg & 1) == 0) {
            int fl = l15 + 16 * (2 * (w & 1) + (cg >> 1));
            unsigned long long* Fw = F + (size_t)(wb * NGRP + gi) * 2048
                                       + kt_w * 128 + fl * 2;
            __hip_atomic_store(Fw,     mine, __ATOMIC_RELAXED, __HIP_MEMORY_SCOPE_AGENT);
            __hip_atomic_store(Fw + 1, part, __ATOMIC_RELAXED, __HIP_MEMORY_SCOPE_AGENT);
        }
        // drain this wave's stores to the coherence point, then post per-wave flag
        asm volatile("s_waitcnt vmcnt(0)" ::: "memory");
        if (lane == 0)
            __hip_atomic_store(gflags + sl * 4 + w, t, __ATOMIC_RELAXED,
                               __HIP_MEMORY_SCOPE_AGENT);
    }

    // ---- final linear: wave 0 of slice-0 WG computes out[b0..b0+15] ----
    if (sl == 0 && w == 0) {
        int spin = 0;
        for (;;) {
            int f = __hip_atomic_load(myflag, __ATOMIC_RELAXED,
                                      __HIP_MEMORY_SCOPE_AGENT);
            if (__all(f >= Tt - 1) || ++spin >= (1 << 20)) break;
        }
        __builtin_amdgcn_sched_barrier(0);
        // final state is in buffer (Tt-1)&1 = 1
        const unsigned long long* Fr = F + (size_t)(1 * NGRP + gi) * 2048 + lane * 2;
        float sum = 0.f;
#pragma unroll
        for (int kt = 0; kt < 16; ++kt) {
            unsigned long long a = __hip_atomic_load(Fr + kt * 128,
                                       __ATOMIC_RELAXED, __HIP_MEMORY_SCOPE_AGENT);
            unsigned long long b = __hip_atomic_load(Fr + kt * 128 + 1,
                                       __ATOMIC_RELAXED, __HIP_MEMORY_SCOPE_AGENT);
            int kbase = kt * 32 + kg8;
#pragma unroll
            for (int j = 0; j < 4; ++j) {
                float fa = __builtin_bit_cast(float,
                              (unsigned)((a >> (16 * j)) & 0xffffu) << 16);
                float fb = __builtin_bit_cast(float,
                              (unsigned)((b >> (16 * j)) & 0xffffu) << 16);
                sum += fa * Wlin[kbase + j] + fb * Wlin[kbase + 4 + j];
            }
        }
        sum += __shfl_xor(sum, 16);
        sum += __shfl_xor(sum, 32);
        if (lane < 16) out[b0 + lane] = sum + blin[0];
    }
}

extern "C" void kernel_launch(void* const* d_in, const int* in_sizes, int n_in,
                              void* d_out, int out_size, void* d_ws, size_t ws_size,
                              hipStream_t stream) {
    const float* x    = (const float*)d_in[0];
    const float* Wih  = (const float*)d_in[1];
    const float* Whh  = (const float*)d_in[2];
    const float* bih  = (const float*)d_in[3];
    const float* bhh  = (const float*)d_in[4];
    const float* Wlin = (const float*)d_in[5];
    const float* blin = (const float*)d_in[6];
    float* out  = (float*)d_out;

    unsigned long long* F = (unsigned long long*)d_ws;      // 2*32*16*64*16B = 1 MB
    int* flags = (int*)((char*)d_ws + 2ull * NGRP * 16 * 64 * 16);

    init_flags<<<4, 256, 0, stream>>>(flags, NGRP * 32);
    gru_persist<<<256, 256, 0, stream>>>(x, Wih, Whh, bih, bhh, Wlin, blin, out,
                                         F, flags);
}